// Round 2
// baseline (1007.511 us; speedup 1.0000x reference)
//
#include <hip/hip_runtime.h>
#include <hip/hip_bf16.h>
#include <stdint.h>

// Problem constants
#define B_ 8
#define L_ 1024
#define D_ 1024
#define H_ 16
#define DH_ 64
#define SCALE_ 0.03125f   // 1/sqrt(1024)

typedef __attribute__((ext_vector_type(8))) short short8_t;   // 8 bf16 in 4 VGPRs
typedef __attribute__((ext_vector_type(4))) float f32x4;

__device__ __forceinline__ unsigned short f2bf(float x) {
  unsigned u = __float_as_uint(x);
  u += 0x7fffu + ((u >> 16) & 1u);   // RNE
  return (unsigned short)(u >> 16);
}
__device__ __forceinline__ float bf2f(unsigned short s) {
  return __uint_as_float(((unsigned)s) << 16);
}

// ---------------- fp32 -> bf16 conversion ----------------
__global__ __launch_bounds__(256) void cvt_kernel(const float* __restrict__ in,
                                                  unsigned short* __restrict__ out, int n4) {
  int i = blockIdx.x * 256 + threadIdx.x;
  if (i >= n4) return;
  float4 f = reinterpret_cast<const float4*>(in)[i];
  ushort4 o;
  o.x = f2bf(f.x); o.y = f2bf(f.y); o.z = f2bf(f.z); o.w = f2bf(f.w);
  reinterpret_cast<ushort4*>(out)[i] = o;
}

// ---------------- bt-GEMM: C[M][N] = A[M][K] @ Bt[N][K]^T + bias ----------------
// A, Bt bf16 K-major. 128x128 tile, BK=32, 256 threads = 4 waves (2x2), 64x64 per wave.
// EPI 0: bf16 row-major out. EPI 1: bf16 transposed out for VT. EPI 2: fp32 out.
template <int EPI>
__global__ __launch_bounds__(256) void gemm_bt(const unsigned short* __restrict__ A,
                                               const unsigned short* __restrict__ Bt,
                                               const float* __restrict__ bias,
                                               void* __restrict__ Cout,
                                               int M, int N, int K) {
  __shared__ __align__(16) unsigned short As[128 * 32];
  __shared__ __align__(16) unsigned short Bs[128 * 32];
  const int tid = threadIdx.x;
  const int lane = tid & 63, wid = tid >> 6;
  const int wr = wid >> 1, wc = wid & 1;
  const int ln15 = lane & 15, hi4 = lane >> 4;
  const int bxn = blockIdx.x * 128;   // N offset
  const int bym = blockIdx.y * 128;   // M offset

  f32x4 acc[4][4];
#pragma unroll
  for (int i = 0; i < 4; ++i)
#pragma unroll
    for (int j = 0; j < 4; ++j) { f32x4 z = {0.f, 0.f, 0.f, 0.f}; acc[i][j] = z; }

  const int r0 = tid >> 2, kc = (tid & 3) * 8;
  const unsigned short* Ab0 = A + (size_t)(bym + r0) * K + kc;
  const unsigned short* Ab1 = A + (size_t)(bym + r0 + 64) * K + kc;
  const unsigned short* Bb0 = Bt + (size_t)(bxn + r0) * K + kc;
  const unsigned short* Bb1 = Bt + (size_t)(bxn + r0 + 64) * K + kc;

  for (int kt = 0; kt < K; kt += 32) {
    uint4 a0 = *reinterpret_cast<const uint4*>(Ab0 + kt);
    uint4 a1 = *reinterpret_cast<const uint4*>(Ab1 + kt);
    uint4 b0 = *reinterpret_cast<const uint4*>(Bb0 + kt);
    uint4 b1 = *reinterpret_cast<const uint4*>(Bb1 + kt);
    __syncthreads();
    reinterpret_cast<uint4*>(As)[tid] = a0;
    reinterpret_cast<uint4*>(As)[tid + 256] = a1;
    reinterpret_cast<uint4*>(Bs)[tid] = b0;
    reinterpret_cast<uint4*>(Bs)[tid + 256] = b1;
    __syncthreads();
    short8_t af[4], bfr[4];
#pragma unroll
    for (int mi = 0; mi < 4; ++mi)
      af[mi] = *reinterpret_cast<const short8_t*>(As + (wr * 64 + mi * 16 + ln15) * 32 + hi4 * 8);
#pragma unroll
    for (int ni = 0; ni < 4; ++ni)
      bfr[ni] = *reinterpret_cast<const short8_t*>(Bs + (wc * 64 + ni * 16 + ln15) * 32 + hi4 * 8);
#pragma unroll
    for (int mi = 0; mi < 4; ++mi)
#pragma unroll
      for (int ni = 0; ni < 4; ++ni)
        acc[mi][ni] = __builtin_amdgcn_mfma_f32_16x16x32_bf16(af[mi], bfr[ni], acc[mi][ni], 0, 0, 0);
  }

#pragma unroll
  for (int mi = 0; mi < 4; ++mi)
#pragma unroll
    for (int ni = 0; ni < 4; ++ni) {
      int row = bym + wr * 64 + mi * 16 + hi4 * 4;
      int col = bxn + wc * 64 + ni * 16 + ln15;
      float bia = bias[col];
#pragma unroll
      for (int r = 0; r < 4; ++r) {
        float v = acc[mi][ni][r] + bia;
        if (EPI == 0) {
          ((unsigned short*)Cout)[(size_t)(row + r) * N + col] = f2bf(v);
        } else if (EPI == 1) {
          int m = row + r;  // m = b*1024 + l ; write VT[b*1024 + col][l]
          ((unsigned short*)Cout)[((size_t)((m >> 10) << 10) + col) * 1024 + (m & 1023)] = f2bf(v);
        } else {
          ((float*)Cout)[(size_t)(row + r) * N + col] = v;
        }
      }
    }
}

// ---------------- attention: scores + mask + softmax + attn-write + PV ----------------
// grid = (L/32, B*H), block = 256 (4 waves). 32 q-rows per block.
__global__ __launch_bounds__(256) void attn_kernel(const unsigned short* __restrict__ Qp,
                                                   const unsigned short* __restrict__ Kp,
                                                   const unsigned short* __restrict__ VT,
                                                   const int* __restrict__ mask,
                                                   float* __restrict__ attn,
                                                   unsigned short* __restrict__ Oh) {
  __shared__ __align__(16) unsigned short S[32 * 1024];  // 64KB, XOR-swizzled rows
  const int tid = threadIdx.x, lane = tid & 63, wid = tid >> 6;
  const int ln15 = lane & 15, hi4 = lane >> 4;
  const int qt = blockIdx.x, bh = blockIdx.y;
  const int b = bh >> 4, h = bh & 15;
  char* Sb = reinterpret_cast<char*>(S);

  // ---- phase 1: raw scores S[32][1024] (bf16, swizzled) ----
  const unsigned short* Qbase = Qp + ((size_t)(b * 1024 + qt * 32)) * 1024 + h * 64;
  const unsigned short* Kbase = Kp + ((size_t)(b * 1024)) * 1024 + h * 64;
  short8_t qf[2][2];
#pragma unroll
  for (int mi = 0; mi < 2; ++mi)
#pragma unroll
    for (int kk = 0; kk < 2; ++kk)
      qf[mi][kk] = *reinterpret_cast<const short8_t*>(Qbase + (size_t)(mi * 16 + ln15) * 1024 + kk * 32 + hi4 * 8);

  for (int sc = 0; sc < 4; ++sc) {
    const int s0 = wid * 256 + sc * 64;
    f32x4 acc[2][4];
#pragma unroll
    for (int i = 0; i < 2; ++i)
#pragma unroll
      for (int j = 0; j < 4; ++j) { f32x4 z = {0.f, 0.f, 0.f, 0.f}; acc[i][j] = z; }
#pragma unroll
    for (int kk = 0; kk < 2; ++kk)
#pragma unroll
      for (int ni = 0; ni < 4; ++ni) {
        short8_t kf = *reinterpret_cast<const short8_t*>(
            Kbase + (size_t)(s0 + ni * 16 + ln15) * 1024 + kk * 32 + hi4 * 8);
#pragma unroll
        for (int mi = 0; mi < 2; ++mi)
          acc[mi][ni] = __builtin_amdgcn_mfma_f32_16x16x32_bf16(qf[mi][kk], kf, acc[mi][ni], 0, 0, 0);
      }
#pragma unroll
    for (int mi = 0; mi < 2; ++mi)
#pragma unroll
      for (int ni = 0; ni < 4; ++ni) {
        int s = s0 + ni * 16 + ln15;
#pragma unroll
        for (int r = 0; r < 4; ++r) {
          int m = mi * 16 + hi4 * 4 + r;
          int byt = (m * 2048 + s * 2) ^ ((m & 7) << 4);
          *reinterpret_cast<unsigned short*>(Sb + byt) = f2bf(acc[mi][ni][r]);
        }
      }
  }
  __syncthreads();

  // ---- phase 2: masked softmax; write attn (fp32) + P (bf16 back to LDS) ----
  {
    const int r = tid >> 3, j = tid & 7;
    const int* mrow = mask + ((size_t)b << 20) + (size_t)(qt * 32 + r) * 1024;
    float rmax = -3.0e38f;
#pragma unroll 4
    for (int i = 0; i < 16; ++i) {
      int c = j + i * 8;
      int byt = (r * 2048 + c * 16) ^ ((r & 7) << 4);
      uint4 u = *reinterpret_cast<const uint4*>(Sb + byt);
      int4 m0 = *reinterpret_cast<const int4*>(mrow + c * 8);
      int4 m1 = *reinterpret_cast<const int4*>(mrow + c * 8 + 4);
      float v0 = m0.x ? bf2f((unsigned short)(u.x & 0xffffu)) * SCALE_ : -1e9f;
      float v1 = m0.y ? bf2f((unsigned short)(u.x >> 16)) * SCALE_ : -1e9f;
      float v2 = m0.z ? bf2f((unsigned short)(u.y & 0xffffu)) * SCALE_ : -1e9f;
      float v3 = m0.w ? bf2f((unsigned short)(u.y >> 16)) * SCALE_ : -1e9f;
      float v4 = m1.x ? bf2f((unsigned short)(u.z & 0xffffu)) * SCALE_ : -1e9f;
      float v5 = m1.y ? bf2f((unsigned short)(u.z >> 16)) * SCALE_ : -1e9f;
      float v6 = m1.z ? bf2f((unsigned short)(u.w & 0xffffu)) * SCALE_ : -1e9f;
      float v7 = m1.w ? bf2f((unsigned short)(u.w >> 16)) * SCALE_ : -1e9f;
      rmax = fmaxf(rmax, fmaxf(fmaxf(fmaxf(v0, v1), fmaxf(v2, v3)), fmaxf(fmaxf(v4, v5), fmaxf(v6, v7))));
    }
    rmax = fmaxf(rmax, __shfl_xor(rmax, 1));
    rmax = fmaxf(rmax, __shfl_xor(rmax, 2));
    rmax = fmaxf(rmax, __shfl_xor(rmax, 4));

    float sum = 0.f;
#pragma unroll 4
    for (int i = 0; i < 16; ++i) {
      int c = j + i * 8;
      int byt = (r * 2048 + c * 16) ^ ((r & 7) << 4);
      uint4 u = *reinterpret_cast<const uint4*>(Sb + byt);
      int4 m0 = *reinterpret_cast<const int4*>(mrow + c * 8);
      int4 m1 = *reinterpret_cast<const int4*>(mrow + c * 8 + 4);
      float e0 = __expf((m0.x ? bf2f((unsigned short)(u.x & 0xffffu)) * SCALE_ : -1e9f) - rmax);
      float e1 = __expf((m0.y ? bf2f((unsigned short)(u.x >> 16)) * SCALE_ : -1e9f) - rmax);
      float e2 = __expf((m0.z ? bf2f((unsigned short)(u.y & 0xffffu)) * SCALE_ : -1e9f) - rmax);
      float e3 = __expf((m0.w ? bf2f((unsigned short)(u.y >> 16)) * SCALE_ : -1e9f) - rmax);
      float e4 = __expf((m1.x ? bf2f((unsigned short)(u.z & 0xffffu)) * SCALE_ : -1e9f) - rmax);
      float e5 = __expf((m1.y ? bf2f((unsigned short)(u.z >> 16)) * SCALE_ : -1e9f) - rmax);
      float e6 = __expf((m1.z ? bf2f((unsigned short)(u.w & 0xffffu)) * SCALE_ : -1e9f) - rmax);
      float e7 = __expf((m1.w ? bf2f((unsigned short)(u.w >> 16)) * SCALE_ : -1e9f) - rmax);
      sum += ((e0 + e1) + (e2 + e3)) + ((e4 + e5) + (e6 + e7));
      uint4 o;
      o.x = (unsigned)f2bf(e0) | ((unsigned)f2bf(e1) << 16);
      o.y = (unsigned)f2bf(e2) | ((unsigned)f2bf(e3) << 16);
      o.z = (unsigned)f2bf(e4) | ((unsigned)f2bf(e5) << 16);
      o.w = (unsigned)f2bf(e6) | ((unsigned)f2bf(e7) << 16);
      *reinterpret_cast<uint4*>(Sb + byt) = o;
    }
    sum += __shfl_xor(sum, 1);
    sum += __shfl_xor(sum, 2);
    sum += __shfl_xor(sum, 4);
    float inv = 1.0f / sum;

    float* arow = attn + ((size_t)bh << 20) + (size_t)(qt * 32 + r) * 1024;
#pragma unroll 4
    for (int i = 0; i < 16; ++i) {
      int c = j + i * 8;
      int byt = (r * 2048 + c * 16) ^ ((r & 7) << 4);
      uint4 u = *reinterpret_cast<const uint4*>(Sb + byt);
      float p0 = bf2f((unsigned short)(u.x & 0xffffu)) * inv;
      float p1 = bf2f((unsigned short)(u.x >> 16)) * inv;
      float p2 = bf2f((unsigned short)(u.y & 0xffffu)) * inv;
      float p3 = bf2f((unsigned short)(u.y >> 16)) * inv;
      float p4 = bf2f((unsigned short)(u.z & 0xffffu)) * inv;
      float p5 = bf2f((unsigned short)(u.z >> 16)) * inv;
      float p6 = bf2f((unsigned short)(u.w & 0xffffu)) * inv;
      float p7 = bf2f((unsigned short)(u.w >> 16)) * inv;
      uint4 o;
      o.x = (unsigned)f2bf(p0) | ((unsigned)f2bf(p1) << 16);
      o.y = (unsigned)f2bf(p2) | ((unsigned)f2bf(p3) << 16);
      o.z = (unsigned)f2bf(p4) | ((unsigned)f2bf(p5) << 16);
      o.w = (unsigned)f2bf(p6) | ((unsigned)f2bf(p7) << 16);
      *reinterpret_cast<uint4*>(Sb + byt) = o;
      float4 f0 = make_float4(p0, p1, p2, p3);
      float4 f1 = make_float4(p4, p5, p6, p7);
      *reinterpret_cast<float4*>(arow + c * 8) = f0;
      *reinterpret_cast<float4*>(arow + c * 8 + 4) = f1;
    }
  }
  __syncthreads();

  // ---- phase 3: O = P @ V ; each wave owns 16 of the 64 head-dims ----
  f32x4 oacc[2];
  { f32x4 z = {0.f, 0.f, 0.f, 0.f}; oacc[0] = z; oacc[1] = z; }
  const unsigned short* Vb = VT + (size_t)(b * 1024 + h * 64 + wid * 16 + ln15) * 1024;
  for (int ks = 0; ks < 32; ++ks) {
    short8_t vfr = *reinterpret_cast<const short8_t*>(Vb + ks * 32 + hi4 * 8);
#pragma unroll
    for (int mi = 0; mi < 2; ++mi) {
      int m = mi * 16 + ln15;
      int byt = (m * 2048 + ks * 64 + hi4 * 16) ^ ((m & 7) << 4);
      short8_t pa = *reinterpret_cast<const short8_t*>(Sb + byt);
      oacc[mi] = __builtin_amdgcn_mfma_f32_16x16x32_bf16(pa, vfr, oacc[mi], 0, 0, 0);
    }
  }
#pragma unroll
  for (int mi = 0; mi < 2; ++mi)
#pragma unroll
    for (int r = 0; r < 4; ++r) {
      int mrow_ = qt * 32 + mi * 16 + hi4 * 4 + r;
      Oh[(size_t)(b * 1024 + mrow_) * 1024 + h * 64 + wid * 16 + ln15] = f2bf(oacc[mi][r]);
    }
}

// ---------------- launcher ----------------
extern "C" void kernel_launch(void* const* d_in, const int* in_sizes, int n_in,
                              void* d_out, int out_size, void* d_ws, size_t ws_size,
                              hipStream_t stream) {
  const float* q = (const float*)d_in[0];
  const float* k = (const float*)d_in[1];
  const float* v = (const float*)d_in[2];
  const int* mask = (const int*)d_in[3];
  const float* wq = (const float*)d_in[4];
  const float* bq = (const float*)d_in[5];
  const float* wk = (const float*)d_in[6];
  const float* bk = (const float*)d_in[7];
  const float* wv = (const float*)d_in[8];
  const float* bv = (const float*)d_in[9];
  const float* wo = (const float*)d_in[10];
  const float* bo = (const float*)d_in[11];

  float* out = (float*)d_out;                    // (B, L, D) = 8388608 floats
  float* attn = out + (size_t)8388608;           // (B, H, L, L)

  char* ws = (char*)d_ws;
  const size_t MB = 1 << 20;
  unsigned short* qb  = (unsigned short*)(ws + 0 * MB);
  unsigned short* kb  = (unsigned short*)(ws + 16 * MB);
  unsigned short* vb  = (unsigned short*)(ws + 32 * MB);
  unsigned short* wqb = (unsigned short*)(ws + 48 * MB);
  unsigned short* wkb = (unsigned short*)(ws + 50 * MB);
  unsigned short* wvb = (unsigned short*)(ws + 52 * MB);
  unsigned short* wob = (unsigned short*)(ws + 54 * MB);
  unsigned short* Qp  = (unsigned short*)(ws + 56 * MB);
  unsigned short* Kp  = (unsigned short*)(ws + 72 * MB);
  unsigned short* VT  = (unsigned short*)(ws + 88 * MB);
  unsigned short* Oh  = (unsigned short*)(ws + 0 * MB);   // aliases qb (dead after Q-proj GEMM)

  // fp32 -> bf16 conversions
  {
    int n4q = (B_ * L_ * D_) / 4;       // 2097152
    int n4w = (D_ * D_) / 4;            // 262144
    cvt_kernel<<<(n4q + 255) / 256, 256, 0, stream>>>(q, qb, n4q);
    cvt_kernel<<<(n4q + 255) / 256, 256, 0, stream>>>(k, kb, n4q);
    cvt_kernel<<<(n4q + 255) / 256, 256, 0, stream>>>(v, vb, n4q);
    cvt_kernel<<<(n4w + 255) / 256, 256, 0, stream>>>(wq, wqb, n4w);
    cvt_kernel<<<(n4w + 255) / 256, 256, 0, stream>>>(wk, wkb, n4w);
    cvt_kernel<<<(n4w + 255) / 256, 256, 0, stream>>>(wv, wvb, n4w);
    cvt_kernel<<<(n4w + 255) / 256, 256, 0, stream>>>(wo, wob, n4w);
  }

  dim3 gg(D_ / 128, (B_ * L_) / 128);   // (8, 64)
  gemm_bt<0><<<gg, 256, 0, stream>>>(qb, wqb, bq, Qp, B_ * L_, D_, D_);
  gemm_bt<0><<<gg, 256, 0, stream>>>(kb, wkb, bk, Kp, B_ * L_, D_, D_);
  gemm_bt<1><<<gg, 256, 0, stream>>>(vb, wvb, bv, VT, B_ * L_, D_, D_);

  attn_kernel<<<dim3(L_ / 32, B_ * H_), 256, 0, stream>>>(Qp, Kp, VT, mask, attn, Oh);

  gemm_bt<2><<<gg, 256, 0, stream>>>(Oh, wob, bo, out, B_ * L_, D_, D_);
}